// Round 8
// baseline (68.324 us; speedup 1.0000x reference)
//
#include <hip/hip_runtime.h>
#include <math.h>

// Problem constants (fixed by setup_inputs()):
#define BATCH   16
#define NQ      4096      // shape_query pts per batch
#define NPRIOR  1024      // prior pts per batch
#define NREC    5120      // reconstructed = concat(shape_query, prior)
#define NMODEL  4096      // model pts per batch
#define NHYP    64

#define NQD1    (BATCH*NREC)        // 81920 dist1 outputs (rec side)
#define NQD2    (BATCH*NMODEL)      // 65536 dist2 outputs (model side)

// Two symmetric row-min passes, 128 rows x 1024 cols per block.
#define P1_RS   (NREC/128)           // 40
#define P1_CB   (NMODEL/1024)        // 4
#define P1_BLOCKS (BATCH*P1_RS*P1_CB)      // 2560
#define P2_RS   (NMODEL/128)         // 32
#define P2_CB   (NREC/1024)          // 5
#define P2_BLOCKS (BATCH*P2_RS*P2_CB)      // 2560
#define GBLOCKS (P1_BLOCKS + P2_BLOCKS)    // 5120

#define WS_WORDS (P1_CB*NQD1 + P2_CB*NQD2 + 1)  // 655361 (~2.62 MB)
#define WS_BYTES ((size_t)WS_WORDS*4)
#define RED_BLOCKS 256

typedef _Float16 half8  __attribute__((ext_vector_type(8)));
typedef float    f32x16 __attribute__((ext_vector_type(16)));

// Single-instruction 3-input min (VOP3).
__device__ __forceinline__ float min3f(float a, float b, float c) {
    float d;
    asm("v_min3_f32 %0, %1, %2, %3" : "=v"(d) : "v"(a), "v"(b), "v"(c));
    return d;
}

// Full-precision f16 packing: distance d = nq + nr - 2 q.r is reproduced to
// ~1e-7 by splitting each value into f16 hi + f16 residual and using all 16
// K-slots of the 32x32x16 MFMA:
//   k0-2 : (-2q)_h * r_h      k3: nq_h*1   k4: 1*nr_h
//   k5-7 : (-2q)_h * r_l
//   k8-10: (-2q)_l * r_h      k11: nq_l*1  k12: 1*nr_l
//   k13-15: 0
// Dropped term: (-2q)_l * r_l ~ 1e-7.  ("query" side = A, "ref" side = B)
__device__ __forceinline__ void packQ2(float x, float y, float z,
                                       half8& hi, half8& lo) {
    float n = fmaf(z, z, fmaf(y, y, x * x));
    float mx = -2.0f * x, my = -2.0f * y, mz = -2.0f * z;
    _Float16 xh = (_Float16)mx, yh = (_Float16)my, zh = (_Float16)mz;
    _Float16 nh = (_Float16)n;
    _Float16 xl = (_Float16)(mx - (float)xh);
    _Float16 yl = (_Float16)(my - (float)yh);
    _Float16 zl = (_Float16)(mz - (float)zh);
    _Float16 nl = (_Float16)(n - (float)nh);
    hi[0] = xh; hi[1] = yh; hi[2] = zh; hi[3] = nh;
    hi[4] = (_Float16)1.0f; hi[5] = xh; hi[6] = yh; hi[7] = zh;
    lo[0] = xl; lo[1] = yl; lo[2] = zl; lo[3] = nl;
    lo[4] = (_Float16)1.0f; lo[5] = (_Float16)0.0f;
    lo[6] = (_Float16)0.0f; lo[7] = (_Float16)0.0f;
}
__device__ __forceinline__ void packR2(float x, float y, float z,
                                       half8& hi, half8& lo) {
    float n = fmaf(z, z, fmaf(y, y, x * x));
    _Float16 xh = (_Float16)x, yh = (_Float16)y, zh = (_Float16)z;
    _Float16 nh = (_Float16)n;
    _Float16 xl = (_Float16)(x - (float)xh);
    _Float16 yl = (_Float16)(y - (float)yh);
    _Float16 zl = (_Float16)(z - (float)zh);
    _Float16 nl = (_Float16)(n - (float)nh);
    hi[0] = xh; hi[1] = yh; hi[2] = zh; hi[3] = (_Float16)1.0f;
    hi[4] = nh; hi[5] = xl; hi[6] = yl; hi[7] = zl;
    lo[0] = xh; lo[1] = yh; lo[2] = zh; lo[3] = (_Float16)1.0f;
    lo[4] = nl; lo[5] = (_Float16)0.0f;
    lo[6] = (_Float16)0.0f; lo[7] = (_Float16)0.0f;
}

__device__ __forceinline__ const float* rec_ptr(
    const float* __restrict__ shape_query, const float* __restrict__ prior,
    int b, int g) {
    return (g < NQ) ? shape_query + ((size_t)b * NQ + g) * 3
                    : prior + ((size_t)b * NPRIOR + (g - NQ)) * 3;
}

// ================= main pass kernel =================
// Each block: 128 rows x 1024 cols; 4 waves x 32 rows. Hot loop per wave:
// 2 ds_read_b128 prefetch + 2 MFMA + 16 v_min3 (32 live result regs, no
// spills). One barrier total. Row-min partial plane written (no atomics).
__global__ __launch_bounds__(256) void chamfer_hp(
    const float* __restrict__ shape_query,
    const float* __restrict__ prior,
    const float* __restrict__ model,
    float* __restrict__ ws, float* __restrict__ out) {
    __shared__ half8 Alds[128 * 2];    // 4 KB  (hi/lo interleaved per point)
    __shared__ half8 Blds[1024 * 2];   // 32 KB

    const int blk = blockIdx.x;
    if (blk == 0 && threadIdx.x == 0) {
        out[2] = 0.0f; out[3] = 0.0f;
        ((unsigned*)ws)[WS_WORDS - 1] = 0u;   // reduce completion counter
    }

    const int t    = threadIdx.x;
    const int wave = t >> 6;
    const int lane = t & 63;
    const int l31  = lane & 31;
    const int kh   = lane >> 5;        // which k-half this lane supplies

    int b, rowbase, colbase;
    float* rowplane;
    const bool pass1 = (blk < P1_BLOCKS);
    if (pass1) {
        b = blk / (P1_RS * P1_CB);
        int rem = blk % (P1_RS * P1_CB);
        int rs = rem / P1_CB, cb = rem % P1_CB;
        rowbase = rs * 128; colbase = cb * 1024;
        rowplane = ws + (size_t)cb * NQD1 + b * NREC + rowbase;
    } else {
        int j = blk - P1_BLOCKS;
        b = j / (P2_RS * P2_CB);
        int rem = j % (P2_RS * P2_CB);
        int rs = rem / P2_CB, cb = rem % P2_CB;
        rowbase = rs * 128; colbase = cb * 1024;
        rowplane = ws + (size_t)P1_CB * NQD1 + (size_t)cb * NQD2
                   + b * NMODEL + rowbase;
    }

    // ---- stage A (128 rows) ----
    if (t < 128) {
        const float* p = pass1
            ? rec_ptr(shape_query, prior, b, rowbase + t)
            : model + ((size_t)b * NMODEL + rowbase + t) * 3;
        half8 hi, lo;
        packQ2(p[0], p[1], p[2], hi, lo);
        Alds[t * 2] = hi; Alds[t * 2 + 1] = lo;
    }
    // ---- stage B (1024 cols) ----
    for (int c = t; c < 1024; c += 256) {
        const float* p = pass1
            ? model + ((size_t)b * NMODEL + colbase + c) * 3
            : rec_ptr(shape_query, prior, b, colbase + c);
        half8 hi, lo;
        packR2(p[0], p[1], p[2], hi, lo);
        Blds[c * 2] = hi; Blds[c * 2 + 1] = lo;
    }
    __syncthreads();   // only barrier

    // A fragment: this wave's 32 rows, this lane's k-half.
    half8 af = Alds[(wave * 32 + l31) * 2 + kh];

    float rmn[16];
#pragma unroll
    for (int r = 0; r < 16; ++r) rmn[r] = 3.0e38f;

    f32x16 cz;
#pragma unroll
    for (int i = 0; i < 16; ++i) cz[i] = 0.0f;

    // Hot loop: 16 iterations of 64 cols (two 32-col tiles).
    half8 bfa = Blds[l31 * 2 + kh];
    half8 bfb = Blds[(32 + l31) * 2 + kh];
#pragma unroll 2
    for (int it = 0; it < 16; ++it) {
        const int nxt = (it == 15) ? 0 : (it + 1) * 64;
        half8 bfa_n = Blds[(nxt + l31) * 2 + kh];
        half8 bfb_n = Blds[(nxt + 32 + l31) * 2 + kh];
        f32x16 da = __builtin_amdgcn_mfma_f32_32x32x16_f16(af, bfa, cz, 0, 0, 0);
        f32x16 db = __builtin_amdgcn_mfma_f32_32x32x16_f16(af, bfb, cz, 0, 0, 0);
#pragma unroll
        for (int r = 0; r < 16; ++r) rmn[r] = min3f(rmn[r], da[r], db[r]);
        bfa = bfa_n; bfb = bfb_n;
    }

    // ---- epilogue: butterfly min over cols (lane&31), write 32 rows ----
#pragma unroll
    for (int r = 0; r < 16; ++r) {
        float v = rmn[r];
        v = fminf(v, __shfl_xor(v, 1, 64));
        v = fminf(v, __shfl_xor(v, 2, 64));
        v = fminf(v, __shfl_xor(v, 4, 64));
        v = fminf(v, __shfl_xor(v, 8, 64));
        v = fminf(v, __shfl_xor(v, 16, 64));
        if (l31 == 0) {
            // C/D row map (32x32): row = (reg&3) + 8*(reg>>2) + 4*(lane>>5)
            int row = wave * 32 + (r & 3) + 8 * (r >> 2) + 4 * kh;
            rowplane[row] = v;
        }
    }
}

// Min over partial planes (4 for dist1, 5 for dist2), sum; last block
// computes the pose loss and writes all 5 outputs.
__global__ __launch_bounds__(256) void reduce_finalize2(
    const float* __restrict__ ws, const float* __restrict__ logits,
    float* __restrict__ out, unsigned int* __restrict__ counter) {
    const float* p1 = ws;
    const float* p2 = ws + (size_t)P1_CB * NQD1;
    float s1 = 0.0f, s2 = 0.0f;
    const int tot = NQD1 + NQD2;
    for (int i = blockIdx.x * 256 + threadIdx.x; i < tot;
         i += RED_BLOCKS * 256) {
        if (i < NQD1) {
            s1 += fminf(fminf(p1[i],            p1[NQD1 + i]),
                        fminf(p1[2 * NQD1 + i], p1[3 * NQD1 + i]));
        } else {
            int j = i - NQD1;
            float v = fminf(fminf(p2[j],            p2[NQD2 + j]),
                            fminf(p2[2 * NQD2 + j], p2[3 * NQD2 + j]));
            s2 += fminf(v, p2[4 * (size_t)NQD2 + j]);
        }
    }
#pragma unroll
    for (int off = 32; off > 0; off >>= 1) {
        s1 += __shfl_xor(s1, off, 64);
        s2 += __shfl_xor(s2, off, 64);
    }
    __shared__ float a1[4], a2[4];
    __shared__ int last;
    int w = threadIdx.x >> 6;
    if ((threadIdx.x & 63) == 0) { a1[w] = s1; a2[w] = s2; }
    __syncthreads();
    if (threadIdx.x == 0) {
        atomicAdd(&out[2], a1[0] + a1[1] + a1[2] + a1[3]);
        atomicAdd(&out[3], a2[0] + a2[1] + a2[2] + a2[3]);
        __threadfence();
        unsigned done = atomicAdd(counter, 1u);
        last = (done == RED_BLOCKS - 1) ? 1 : 0;
    }
    __syncthreads();
    if (last && threadIdx.x < 64) {
        const int lane = threadIdx.x;
        float pose_part = 0.0f;
        if (lane < BATCH) {
            const float* L = logits + lane * NHYP;
            float mx = L[0];
#pragma unroll 8
            for (int j = 1; j < NHYP; ++j) mx = fmaxf(mx, L[j]);
            float s = 0.0f;
#pragma unroll 8
            for (int j = 0; j < NHYP; ++j) s += expf(L[j] - mx);
            pose_part = L[0] - (mx + logf(s));  // log_prob[b, 0]
        }
#pragma unroll
        for (int off = 8; off > 0; off >>= 1)
            pose_part += __shfl_xor(pose_part, off, 64);
        if (lane == 0) {
            float sum1 = atomicAdd(&out[2], 0.0f);
            float sum2 = atomicAdd(&out[3], 0.0f);
            float shape_loss = sum1 / (float)NQD1 + sum2 / (float)NQD2;
            float pose_loss = -pose_part / (float)BATCH;
            out[0] = 0.4f * pose_loss + 0.6f * shape_loss;
            out[1] = pose_loss;
            out[2] = shape_loss;
            out[3] = shape_loss;  // sdf_loss
            out[4] = shape_loss;  // caption_loss
        }
    }
}

// ================= fallback (tiny ws) =================

__global__ void init_out(float* out) {
    if (threadIdx.x == 0) { out[2] = 0.0f; out[3] = 0.0f; }
}

__device__ __forceinline__ void scan_refs(const float* __restrict__ r, int cnt,
                                          float px, float py, float pz,
                                          float& minv) {
    for (int m = 0; m < cnt; m += 8) {
#pragma unroll
        for (int u = 0; u < 8; ++u) {
            float mx = r[(m + u) * 3 + 0];
            float my = r[(m + u) * 3 + 1];
            float mz = r[(m + u) * 3 + 2];
            float dx = px - mx, dy = py - my, dz = pz - mz;
            float d = fmaf(dz, dz, fmaf(dy, dy, dx * dx));
            minv = fminf(minv, d);
        }
    }
}

__global__ __launch_bounds__(64) void chamfer_sum(
    const float* __restrict__ qa, int na_, const float* __restrict__ qb, int nb_,
    const float* __restrict__ ra, int ma, const float* __restrict__ rb, int mb,
    float* __restrict__ accum) {
    const int b = blockIdx.y;
    const int n = blockIdx.x * 64 + threadIdx.x;
    float px, py, pz;
    if (n < na_) {
        const float* p = qa + ((size_t)b * na_ + n) * 3;
        px = p[0]; py = p[1]; pz = p[2];
    } else {
        const float* p = qb + ((size_t)b * nb_ + (n - na_)) * 3;
        px = p[0]; py = p[1]; pz = p[2];
    }
    float minv = 3.0e38f;
    scan_refs(ra + (size_t)b * ma * 3, ma, px, py, pz, minv);
    if (mb > 0) scan_refs(rb + (size_t)b * mb * 3, mb, px, py, pz, minv);
    float s = minv;
#pragma unroll
    for (int off = 32; off > 0; off >>= 1) s += __shfl_xor(s, off, 64);
    if (threadIdx.x == 0) atomicAdd(accum, s);
}

__global__ __launch_bounds__(64) void finalize_kernel(
    const float* __restrict__ logits, float* __restrict__ out) {
    const int lane = threadIdx.x;
    float pose_part = 0.0f;
    if (lane < BATCH) {
        const float* L = logits + lane * NHYP;
        float mx = L[0];
#pragma unroll 8
        for (int j = 1; j < NHYP; ++j) mx = fmaxf(mx, L[j]);
        float s = 0.0f;
#pragma unroll 8
        for (int j = 0; j < NHYP; ++j) s += expf(L[j] - mx);
        pose_part = L[0] - (mx + logf(s));
    }
#pragma unroll
    for (int off = 8; off > 0; off >>= 1) pose_part += __shfl_xor(pose_part, off, 64);
    if (lane == 0) {
        float shape_loss = out[2] / (float)NQD1 + out[3] / (float)NQD2;
        float pose_loss = -pose_part / (float)BATCH;
        out[0] = 0.4f * pose_loss + 0.6f * shape_loss;
        out[1] = pose_loss;
        out[2] = shape_loss;
        out[3] = shape_loss;
        out[4] = shape_loss;
    }
}

extern "C" void kernel_launch(void* const* d_in, const int* in_sizes, int n_in,
                              void* d_out, int out_size, void* d_ws, size_t ws_size,
                              hipStream_t stream) {
    const float* shape_query = (const float*)d_in[0];  // (16,4096,3)
    const float* logits      = (const float*)d_in[1];  // (16,64)
    const float* prior       = (const float*)d_in[5];  // (16,1024,3)
    const float* model       = (const float*)d_in[6];  // (16,4096,3)
    float* out = (float*)d_out;

    if (ws_size >= WS_BYTES) {
        float* ws = (float*)d_ws;
        unsigned int* counter = (unsigned int*)ws + (WS_WORDS - 1);
        hipLaunchKernelGGL(chamfer_hp, dim3(GBLOCKS), dim3(256), 0, stream,
                           shape_query, prior, model, ws, out);
        hipLaunchKernelGGL(reduce_finalize2, dim3(RED_BLOCKS), dim3(256), 0,
                           stream, ws, logits, out, counter);
    } else {
        hipLaunchKernelGGL(init_out, dim3(1), dim3(64), 0, stream, out);
        hipLaunchKernelGGL(chamfer_sum,
                           dim3(NREC / 64, BATCH), dim3(64), 0, stream,
                           shape_query, NQ, prior, NPRIOR,
                           model, NMODEL, (const float*)nullptr, 0, out + 2);
        hipLaunchKernelGGL(chamfer_sum,
                           dim3(NMODEL / 64, BATCH), dim3(64), 0, stream,
                           model, NMODEL, (const float*)nullptr, 0,
                           shape_query, NQ, prior, NPRIOR, out + 3);
        hipLaunchKernelGGL(finalize_kernel, dim3(1), dim3(64), 0, stream,
                           logits, out);
    }
}

// Round 11
// 67.851 us; speedup vs baseline: 1.0070x; 1.0070x over previous
//
#include <hip/hip_runtime.h>
#include <math.h>

// Problem constants (fixed by setup_inputs()):
#define BATCH   16
#define NQ      4096      // shape_query pts per batch
#define NPRIOR  1024      // prior pts per batch
#define NREC    5120      // reconstructed = concat(shape_query, prior)
#define NMODEL  4096      // model pts per batch
#define NHYP    64

#define NQD1    (BATCH*NREC)        // 81920 dist1 outputs (rec side)
#define NQD2    (BATCH*NMODEL)      // 65536 dist2 outputs (model side)

// Two symmetric row-min passes, 128 rows x 1024 cols per block (round 8).
#define P1_RS   (NREC/128)           // 40
#define P1_CB   (NMODEL/1024)        // 4
#define P1_BLOCKS (BATCH*P1_RS*P1_CB)      // 2560
#define P2_RS   (NMODEL/128)         // 32
#define P2_CB   (NREC/1024)          // 5
#define P2_BLOCKS (BATCH*P2_RS*P2_CB)      // 2560
#define GBLOCKS (P1_BLOCKS + P2_BLOCKS)    // 5120

#define WS_WORDS (P1_CB*NQD1 + P2_CB*NQD2 + 1)  // 655361 (~2.62 MB)
#define WS_BYTES ((size_t)WS_WORDS*4)
#define RED_BLOCKS 256

typedef _Float16 half8  __attribute__((ext_vector_type(8)));
typedef float    f32x16 __attribute__((ext_vector_type(16)));

// Single-instruction 3-input min (VOP3).
__device__ __forceinline__ float min3f(float a, float b, float c) {
    float d;
    asm("v_min3_f32 %0, %1, %2, %3" : "=v"(d) : "v"(a), "v"(b), "v"(c));
    return d;
}

// Full-precision f16 packing (validated round 8, absmax 0.0):
// d = nq + nr - 2 q.r using all 16 K-slots of the 32x32x16 MFMA.
// The slot->k mapping is irrelevant: A and B use the same lane/element map,
// so the dot pairs A-slot with B-slot elementwise.
//   hi-slots: (-2q)_h*r_h (x,y,z), nq_h*1, 1*nr_h, (-2q)_h*r_l (x,y,z)
//   lo-slots: (-2q)_l*r_h (x,y,z), nq_l*1, 1*nr_l, 0,0,0
// Dropped term (-2q)_l*r_l ~ 1e-7.
__device__ __forceinline__ void packQ2(float x, float y, float z,
                                       half8& hi, half8& lo) {
    float n = fmaf(z, z, fmaf(y, y, x * x));
    float mx = -2.0f * x, my = -2.0f * y, mz = -2.0f * z;
    _Float16 xh = (_Float16)mx, yh = (_Float16)my, zh = (_Float16)mz;
    _Float16 nh = (_Float16)n;
    _Float16 xl = (_Float16)(mx - (float)xh);
    _Float16 yl = (_Float16)(my - (float)yh);
    _Float16 zl = (_Float16)(mz - (float)zh);
    _Float16 nl = (_Float16)(n - (float)nh);
    hi[0] = xh; hi[1] = yh; hi[2] = zh; hi[3] = nh;
    hi[4] = (_Float16)1.0f; hi[5] = xh; hi[6] = yh; hi[7] = zh;
    lo[0] = xl; lo[1] = yl; lo[2] = zl; lo[3] = nl;
    lo[4] = (_Float16)1.0f; lo[5] = (_Float16)0.0f;
    lo[6] = (_Float16)0.0f; lo[7] = (_Float16)0.0f;
}
__device__ __forceinline__ void packR2(float x, float y, float z,
                                       half8& hi, half8& lo) {
    float n = fmaf(z, z, fmaf(y, y, x * x));
    _Float16 xh = (_Float16)x, yh = (_Float16)y, zh = (_Float16)z;
    _Float16 nh = (_Float16)n;
    _Float16 xl = (_Float16)(x - (float)xh);
    _Float16 yl = (_Float16)(y - (float)yh);
    _Float16 zl = (_Float16)(z - (float)zh);
    _Float16 nl = (_Float16)(n - (float)nh);
    hi[0] = xh; hi[1] = yh; hi[2] = zh; hi[3] = (_Float16)1.0f;
    hi[4] = nh; hi[5] = xl; hi[6] = yl; hi[7] = zl;
    lo[0] = xh; lo[1] = yh; lo[2] = zh; lo[3] = (_Float16)1.0f;
    lo[4] = nl; lo[5] = (_Float16)0.0f;
    lo[6] = (_Float16)0.0f; lo[7] = (_Float16)0.0f;
}

__device__ __forceinline__ const float* rec_ptr(
    const float* __restrict__ shape_query, const float* __restrict__ prior,
    int b, int g) {
    return (g < NQ) ? shape_query + ((size_t)b * NQ + g) * 3
                    : prior + ((size_t)b * NPRIOR + (g - NQ)) * 3;
}

// ================= main pass kernel (round 8 + de-interleaved LDS) ========
// Each block: 128 rows x 1024 cols; 4 waves x 32 rows. ONLY change vs the
// passing round-8 kernel: hi/lo fragments live in separate flat planes
// ([kh*N + idx], uniform base + divergent index), so each 32-lane half
// reads contiguous 16B-stride ds_read_b128 -> conflict-free. Round 8's
// [idx*2 + kh] interleave (32B stride) was an 8-way bank conflict (4.18M).
__global__ __launch_bounds__(256) void chamfer_hp(
    const float* __restrict__ shape_query,
    const float* __restrict__ prior,
    const float* __restrict__ model,
    float* __restrict__ ws, float* __restrict__ out) {
    __shared__ half8 Alds2[2 * 128];     // [kh][row]   4 KB
    __shared__ half8 Blds2[2 * 1024];    // [kh][col]  32 KB

    const int blk = blockIdx.x;
    if (blk == 0 && threadIdx.x == 0) {
        out[2] = 0.0f; out[3] = 0.0f;
        ((unsigned*)ws)[WS_WORDS - 1] = 0u;   // reduce completion counter
    }

    const int t    = threadIdx.x;
    const int wave = t >> 6;
    const int lane = t & 63;
    const int l31  = lane & 31;
    const int kh   = lane >> 5;        // which k-half this lane supplies

    int b, rowbase, colbase;
    float* rowplane;
    const bool pass1 = (blk < P1_BLOCKS);
    if (pass1) {
        b = blk / (P1_RS * P1_CB);
        int rem = blk % (P1_RS * P1_CB);
        int rs = rem / P1_CB, cb = rem % P1_CB;
        rowbase = rs * 128; colbase = cb * 1024;
        rowplane = ws + (size_t)cb * NQD1 + b * NREC + rowbase;
    } else {
        int j = blk - P1_BLOCKS;
        b = j / (P2_RS * P2_CB);
        int rem = j % (P2_RS * P2_CB);
        int rs = rem / P2_CB, cb = rem % P2_CB;
        rowbase = rs * 128; colbase = cb * 1024;
        rowplane = ws + (size_t)P1_CB * NQD1 + (size_t)cb * NQD2
                   + b * NMODEL + rowbase;
    }

    // ---- stage A (128 rows) ----
    if (t < 128) {
        const float* p = pass1
            ? rec_ptr(shape_query, prior, b, rowbase + t)
            : model + ((size_t)b * NMODEL + rowbase + t) * 3;
        half8 hi, lo;
        packQ2(p[0], p[1], p[2], hi, lo);
        Alds2[t] = hi; Alds2[128 + t] = lo;
    }
    // ---- stage B (1024 cols) ----
    for (int c = t; c < 1024; c += 256) {
        const float* p = pass1
            ? model + ((size_t)b * NMODEL + colbase + c) * 3
            : rec_ptr(shape_query, prior, b, colbase + c);
        half8 hi, lo;
        packR2(p[0], p[1], p[2], hi, lo);
        Blds2[c] = hi; Blds2[1024 + c] = lo;
    }
    __syncthreads();   // only barrier

    // A fragment: this wave's 32 rows, this lane's k-half.
    half8 af = Alds2[kh * 128 + wave * 32 + l31];

    float rmn[16];
#pragma unroll
    for (int r = 0; r < 16; ++r) rmn[r] = 3.0e38f;

    f32x16 cz;
#pragma unroll
    for (int i = 0; i < 16; ++i) cz[i] = 0.0f;

    const int boff = kh * 1024;   // uniform base + divergent index

    // Hot loop: 16 iterations of 64 cols (two 32-col tiles).
    half8 bfa = Blds2[boff + l31];
    half8 bfb = Blds2[boff + 32 + l31];
#pragma unroll 2
    for (int it = 0; it < 16; ++it) {
        const int nxt = (it == 15) ? 0 : (it + 1) * 64;
        half8 bfa_n = Blds2[boff + nxt + l31];
        half8 bfb_n = Blds2[boff + nxt + 32 + l31];
        f32x16 da = __builtin_amdgcn_mfma_f32_32x32x16_f16(af, bfa, cz, 0, 0, 0);
        f32x16 db = __builtin_amdgcn_mfma_f32_32x32x16_f16(af, bfb, cz, 0, 0, 0);
#pragma unroll
        for (int r = 0; r < 16; ++r) rmn[r] = min3f(rmn[r], da[r], db[r]);
        bfa = bfa_n; bfb = bfb_n;
    }

    // ---- epilogue: butterfly min over cols (lane&31), write 32 rows ----
#pragma unroll
    for (int r = 0; r < 16; ++r) {
        float v = rmn[r];
        v = fminf(v, __shfl_xor(v, 1, 64));
        v = fminf(v, __shfl_xor(v, 2, 64));
        v = fminf(v, __shfl_xor(v, 4, 64));
        v = fminf(v, __shfl_xor(v, 8, 64));
        v = fminf(v, __shfl_xor(v, 16, 64));
        if (l31 == 0) {
            // C/D row map (32x32): row = (reg&3) + 8*(reg>>2) + 4*(lane>>5)
            int row = wave * 32 + (r & 3) + 8 * (r >> 2) + 4 * kh;
            rowplane[row] = v;
        }
    }
}

// Min over partial planes (4 for dist1, 5 for dist2), sum; last block
// computes the pose loss and writes all 5 outputs.  (Round 8, verbatim.)
__global__ __launch_bounds__(256) void reduce_finalize2(
    const float* __restrict__ ws, const float* __restrict__ logits,
    float* __restrict__ out, unsigned int* __restrict__ counter) {
    const float* p1 = ws;
    const float* p2 = ws + (size_t)P1_CB * NQD1;
    float s1 = 0.0f, s2 = 0.0f;
    const int tot = NQD1 + NQD2;
    for (int i = blockIdx.x * 256 + threadIdx.x; i < tot;
         i += RED_BLOCKS * 256) {
        if (i < NQD1) {
            s1 += fminf(fminf(p1[i],            p1[NQD1 + i]),
                        fminf(p1[2 * NQD1 + i], p1[3 * NQD1 + i]));
        } else {
            int j = i - NQD1;
            float v = fminf(fminf(p2[j],            p2[NQD2 + j]),
                            fminf(p2[2 * NQD2 + j], p2[3 * NQD2 + j]));
            s2 += fminf(v, p2[4 * (size_t)NQD2 + j]);
        }
    }
#pragma unroll
    for (int off = 32; off > 0; off >>= 1) {
        s1 += __shfl_xor(s1, off, 64);
        s2 += __shfl_xor(s2, off, 64);
    }
    __shared__ float a1[4], a2[4];
    __shared__ int last;
    int w = threadIdx.x >> 6;
    if ((threadIdx.x & 63) == 0) { a1[w] = s1; a2[w] = s2; }
    __syncthreads();
    if (threadIdx.x == 0) {
        atomicAdd(&out[2], a1[0] + a1[1] + a1[2] + a1[3]);
        atomicAdd(&out[3], a2[0] + a2[1] + a2[2] + a2[3]);
        __threadfence();
        unsigned done = atomicAdd(counter, 1u);
        last = (done == RED_BLOCKS - 1) ? 1 : 0;
    }
    __syncthreads();
    if (last && threadIdx.x < 64) {
        const int lane = threadIdx.x;
        float pose_part = 0.0f;
        if (lane < BATCH) {
            const float* L = logits + lane * NHYP;
            float mx = L[0];
#pragma unroll 8
            for (int j = 1; j < NHYP; ++j) mx = fmaxf(mx, L[j]);
            float s = 0.0f;
#pragma unroll 8
            for (int j = 0; j < NHYP; ++j) s += expf(L[j] - mx);
            pose_part = L[0] - (mx + logf(s));  // log_prob[b, 0]
        }
#pragma unroll
        for (int off = 8; off > 0; off >>= 1)
            pose_part += __shfl_xor(pose_part, off, 64);
        if (lane == 0) {
            float sum1 = atomicAdd(&out[2], 0.0f);
            float sum2 = atomicAdd(&out[3], 0.0f);
            float shape_loss = sum1 / (float)NQD1 + sum2 / (float)NQD2;
            float pose_loss = -pose_part / (float)BATCH;
            out[0] = 0.4f * pose_loss + 0.6f * shape_loss;
            out[1] = pose_loss;
            out[2] = shape_loss;
            out[3] = shape_loss;  // sdf_loss
            out[4] = shape_loss;  // caption_loss
        }
    }
}

// ================= fallback (tiny ws) =================

__global__ void init_out(float* out) {
    if (threadIdx.x == 0) { out[2] = 0.0f; out[3] = 0.0f; }
}

__device__ __forceinline__ void scan_refs(const float* __restrict__ r, int cnt,
                                          float px, float py, float pz,
                                          float& minv) {
    for (int m = 0; m < cnt; m += 8) {
#pragma unroll
        for (int u = 0; u < 8; ++u) {
            float mx = r[(m + u) * 3 + 0];
            float my = r[(m + u) * 3 + 1];
            float mz = r[(m + u) * 3 + 2];
            float dx = px - mx, dy = py - my, dz = pz - mz;
            float d = fmaf(dz, dz, fmaf(dy, dy, dx * dx));
            minv = fminf(minv, d);
        }
    }
}

__global__ __launch_bounds__(64) void chamfer_sum(
    const float* __restrict__ qa, int na_, const float* __restrict__ qb, int nb_,
    const float* __restrict__ ra, int ma, const float* __restrict__ rb, int mb,
    float* __restrict__ accum) {
    const int b = blockIdx.y;
    const int n = blockIdx.x * 64 + threadIdx.x;
    float px, py, pz;
    if (n < na_) {
        const float* p = qa + ((size_t)b * na_ + n) * 3;
        px = p[0]; py = p[1]; pz = p[2];
    } else {
        const float* p = qb + ((size_t)b * nb_ + (n - na_)) * 3;
        px = p[0]; py = p[1]; pz = p[2];
    }
    float minv = 3.0e38f;
    scan_refs(ra + (size_t)b * ma * 3, ma, px, py, pz, minv);
    if (mb > 0) scan_refs(rb + (size_t)b * mb * 3, mb, px, py, pz, minv);
    float s = minv;
#pragma unroll
    for (int off = 32; off > 0; off >>= 1) s += __shfl_xor(s, off, 64);
    if (threadIdx.x == 0) atomicAdd(accum, s);
}

__global__ __launch_bounds__(64) void finalize_kernel(
    const float* __restrict__ logits, float* __restrict__ out) {
    const int lane = threadIdx.x;
    float pose_part = 0.0f;
    if (lane < BATCH) {
        const float* L = logits + lane * NHYP;
        float mx = L[0];
#pragma unroll 8
        for (int j = 1; j < NHYP; ++j) mx = fmaxf(mx, L[j]);
        float s = 0.0f;
#pragma unroll 8
        for (int j = 0; j < NHYP; ++j) s += expf(L[j] - mx);
        pose_part = L[0] - (mx + logf(s));
    }
#pragma unroll
    for (int off = 8; off > 0; off >>= 1) pose_part += __shfl_xor(pose_part, off, 64);
    if (lane == 0) {
        float shape_loss = out[2] / (float)NQD1 + out[3] / (float)NQD2;
        float pose_loss = -pose_part / (float)BATCH;
        out[0] = 0.4f * pose_loss + 0.6f * shape_loss;
        out[1] = pose_loss;
        out[2] = shape_loss;
        out[3] = shape_loss;
        out[4] = shape_loss;
    }
}

extern "C" void kernel_launch(void* const* d_in, const int* in_sizes, int n_in,
                              void* d_out, int out_size, void* d_ws, size_t ws_size,
                              hipStream_t stream) {
    const float* shape_query = (const float*)d_in[0];  // (16,4096,3)
    const float* logits      = (const float*)d_in[1];  // (16,64)
    const float* prior       = (const float*)d_in[5];  // (16,1024,3)
    const float* model       = (const float*)d_in[6];  // (16,4096,3)
    float* out = (float*)d_out;

    if (ws_size >= WS_BYTES) {
        float* ws = (float*)d_ws;
        unsigned int* counter = (unsigned int*)ws + (WS_WORDS - 1);
        hipLaunchKernelGGL(chamfer_hp, dim3(GBLOCKS), dim3(256), 0, stream,
                           shape_query, prior, model, ws, out);
        hipLaunchKernelGGL(reduce_finalize2, dim3(RED_BLOCKS), dim3(256), 0,
                           stream, ws, logits, out, counter);
    } else {
        hipLaunchKernelGGL(init_out, dim3(1), dim3(64), 0, stream, out);
        hipLaunchKernelGGL(chamfer_sum,
                           dim3(NREC / 64, BATCH), dim3(64), 0, stream,
                           shape_query, NQ, prior, NPRIOR,
                           model, NMODEL, (const float*)nullptr, 0, out + 2);
        hipLaunchKernelGGL(chamfer_sum,
                           dim3(NMODEL / 64, BATCH), dim3(64), 0, stream,
                           model, NMODEL, (const float*)nullptr, 0,
                           shape_query, NQ, prior, NPRIOR, out + 3);
        hipLaunchKernelGGL(finalize_kernel, dim3(1), dim3(64), 0, stream,
                           logits, out);
    }
}

// Round 13
// 60.351 us; speedup vs baseline: 1.1321x; 1.1243x over previous
//
#include <hip/hip_runtime.h>
#include <math.h>

// Problem constants (fixed by setup_inputs()):
#define BATCH   16
#define NQ      4096      // shape_query pts per batch
#define NPRIOR  1024      // prior pts per batch
#define NREC    5120      // reconstructed = concat(shape_query, prior)
#define NMODEL  4096      // model pts per batch
#define NHYP    64

#define NQD1    (BATCH*NREC)        // 81920 dist1 outputs (rec side)
#define NQD2    (BATCH*NMODEL)      // 65536 dist2 outputs (model side)

// FROZEN validated shape (rounds 8/11): 128 rows/block, 4 waves x 32 rows,
// 1 A-frag/wave, 2 MFMA + 16 v_min3 per 64-col step. 256-row A staging is
// known-broken (rounds 9/10/12) -- do not revisit.
// NEW: each block loops over ALL cols of its batch in 512-col tiles,
// accumulating rmn across tiles -> rowplane holds FINAL mins (no planes).
#define TILE_COLS 512
#define P1_ROWBLKS (NREC/128)        // 40
#define P2_ROWBLKS (NMODEL/128)      // 32
#define P1_BLOCKS (BATCH*P1_ROWBLKS)       // 640
#define P2_BLOCKS (BATCH*P2_ROWBLKS)       // 512
#define GBLOCKS   (P1_BLOCKS + P2_BLOCKS)  // 1152
#define P1_NTILES (NMODEL/TILE_COLS)       // 8
#define P2_NTILES (NREC/TILE_COLS)         // 10

#define WS_WORDS (NQD1 + NQD2 + 1)   // 147457 (~590 KB) + counter
#define WS_BYTES ((size_t)WS_WORDS*4)
#define RED_BLOCKS 128

typedef _Float16 half8  __attribute__((ext_vector_type(8)));
typedef float    f32x16 __attribute__((ext_vector_type(16)));

// Single-instruction 3-input min (VOP3).
__device__ __forceinline__ float min3f(float a, float b, float c) {
    float d;
    asm("v_min3_f32 %0, %1, %2, %3" : "=v"(d) : "v"(a), "v"(b), "v"(c));
    return d;
}

// Full-precision f16 packing (validated rounds 8 & 11, absmax 0.0):
// d = nq + nr - 2 q.r using all 16 K-slots of the 32x32x16 MFMA.
//   hi-slots: (-2q)_h*r_h (x,y,z), nq_h*1, 1*nr_h, (-2q)_h*r_l (x,y,z)
//   lo-slots: (-2q)_l*r_h (x,y,z), nq_l*1, 1*nr_l, 0,0,0
// Dropped term (-2q)_l*r_l ~ 1e-7.
__device__ __forceinline__ void packQ2(float x, float y, float z,
                                       half8& hi, half8& lo) {
    float n = fmaf(z, z, fmaf(y, y, x * x));
    float mx = -2.0f * x, my = -2.0f * y, mz = -2.0f * z;
    _Float16 xh = (_Float16)mx, yh = (_Float16)my, zh = (_Float16)mz;
    _Float16 nh = (_Float16)n;
    _Float16 xl = (_Float16)(mx - (float)xh);
    _Float16 yl = (_Float16)(my - (float)yh);
    _Float16 zl = (_Float16)(mz - (float)zh);
    _Float16 nl = (_Float16)(n - (float)nh);
    hi[0] = xh; hi[1] = yh; hi[2] = zh; hi[3] = nh;
    hi[4] = (_Float16)1.0f; hi[5] = xh; hi[6] = yh; hi[7] = zh;
    lo[0] = xl; lo[1] = yl; lo[2] = zl; lo[3] = nl;
    lo[4] = (_Float16)1.0f; lo[5] = (_Float16)0.0f;
    lo[6] = (_Float16)0.0f; lo[7] = (_Float16)0.0f;
}
__device__ __forceinline__ void packR2(float x, float y, float z,
                                       half8& hi, half8& lo) {
    float n = fmaf(z, z, fmaf(y, y, x * x));
    _Float16 xh = (_Float16)x, yh = (_Float16)y, zh = (_Float16)z;
    _Float16 nh = (_Float16)n;
    _Float16 xl = (_Float16)(x - (float)xh);
    _Float16 yl = (_Float16)(y - (float)yh);
    _Float16 zl = (_Float16)(z - (float)zh);
    _Float16 nl = (_Float16)(n - (float)nh);
    hi[0] = xh; hi[1] = yh; hi[2] = zh; hi[3] = (_Float16)1.0f;
    hi[4] = nh; hi[5] = xl; hi[6] = yl; hi[7] = zl;
    lo[0] = xh; lo[1] = yh; lo[2] = zh; lo[3] = (_Float16)1.0f;
    lo[4] = nl; lo[5] = (_Float16)0.0f;
    lo[6] = (_Float16)0.0f; lo[7] = (_Float16)0.0f;
}

__device__ __forceinline__ const float* rec_ptr(
    const float* __restrict__ shape_query, const float* __restrict__ prior,
    int b, int g) {
    return (g < NQ) ? shape_query + ((size_t)b * NQ + g) * 3
                    : prior + ((size_t)b * NPRIOR + (g - NQ)) * 3;
}

// ================= main pass kernel =================
// Per block: 128 rows x (all cols of batch), col-tiled at 512.
// LDS 20 KB -> 8 blocks/CU = 32 waves/CU (round 11 was 36KB -> 12 waves/CU,
// occupancy 37%, latency-bound). Hot loop & epilogue byte-equivalent to the
// validated round-11 kernel; only the tile loop + staging cadence is new.
__global__ __launch_bounds__(256) void chamfer_hp(
    const float* __restrict__ shape_query,
    const float* __restrict__ prior,
    const float* __restrict__ model,
    float* __restrict__ ws, float* __restrict__ out) {
    __shared__ half8 Alds2[2 * 128];        // [kh][row]   4 KB
    __shared__ half8 Blds2[2 * TILE_COLS];  // [kh][col]  16 KB

    const int blk = blockIdx.x;
    if (blk == 0 && threadIdx.x == 0) {
        out[2] = 0.0f; out[3] = 0.0f;
        ((unsigned*)ws)[WS_WORDS - 1] = 0u;   // reduce completion counter
    }

    const int t    = threadIdx.x;
    const int wave = t >> 6;
    const int lane = t & 63;
    const int l31  = lane & 31;
    const int kh   = lane >> 5;        // which k-half this lane supplies

    int b, rowbase, ntiles;
    float* rowplane;
    const bool pass1 = (blk < P1_BLOCKS);
    if (pass1) {
        b = blk / P1_ROWBLKS;
        rowbase = (blk % P1_ROWBLKS) * 128;
        ntiles = P1_NTILES;
        rowplane = ws + (size_t)b * NREC + rowbase;
    } else {
        int j = blk - P1_BLOCKS;
        b = j / P2_ROWBLKS;
        rowbase = (j % P2_ROWBLKS) * 128;
        ntiles = P2_NTILES;
        rowplane = ws + NQD1 + (size_t)b * NMODEL + rowbase;
    }

    // ---- stage A (128 rows, once) ----
    if (t < 128) {
        const float* p = pass1
            ? rec_ptr(shape_query, prior, b, rowbase + t)
            : model + ((size_t)b * NMODEL + rowbase + t) * 3;
        half8 hi, lo;
        packQ2(p[0], p[1], p[2], hi, lo);
        Alds2[t] = hi; Alds2[128 + t] = lo;
    }

    float rmn[16];
#pragma unroll
    for (int r = 0; r < 16; ++r) rmn[r] = 3.0e38f;

    f32x16 cz;
#pragma unroll
    for (int i = 0; i < 16; ++i) cz[i] = 0.0f;

    const int boff = kh * TILE_COLS;   // uniform base + divergent index
    half8 af;

    for (int tile = 0; tile < ntiles; ++tile) {
        if (tile) __syncthreads();     // all reads of previous tile done
        // ---- stage B tile (512 cols, 2/thread) ----
        const int colbase = tile * TILE_COLS;
#pragma unroll
        for (int c = t; c < TILE_COLS; c += 256) {
            const float* p = pass1
                ? model + ((size_t)b * NMODEL + colbase + c) * 3
                : rec_ptr(shape_query, prior, b, colbase + c);
            half8 hi, lo;
            packR2(p[0], p[1], p[2], hi, lo);
            Blds2[c] = hi; Blds2[TILE_COLS + c] = lo;
        }
        __syncthreads();               // B (and A on tile 0) visible

        // A fragment: this wave's 32 rows, this lane's k-half (re-read per
        // tile -- 1 ds_read_b128, negligible; keeps barrier ordering clean).
        af = Alds2[kh * 128 + wave * 32 + l31];

        // Hot loop: 8 iterations of 64 cols (two 32-col B-frags).
        half8 bfa = Blds2[boff + l31];
        half8 bfb = Blds2[boff + 32 + l31];
#pragma unroll 2
        for (int it = 0; it < TILE_COLS / 64; ++it) {
            const int nxt = (it == TILE_COLS / 64 - 1) ? 0 : (it + 1) * 64;
            half8 bfa_n = Blds2[boff + nxt + l31];
            half8 bfb_n = Blds2[boff + nxt + 32 + l31];
            f32x16 da = __builtin_amdgcn_mfma_f32_32x32x16_f16(af, bfa, cz, 0, 0, 0);
            f32x16 db = __builtin_amdgcn_mfma_f32_32x32x16_f16(af, bfb, cz, 0, 0, 0);
#pragma unroll
            for (int r = 0; r < 16; ++r) rmn[r] = min3f(rmn[r], da[r], db[r]);
            bfa = bfa_n; bfb = bfb_n;
        }
    }

    // ---- epilogue: butterfly min over cols (lane&31), write 32 FINAL rows --
#pragma unroll
    for (int r = 0; r < 16; ++r) {
        float v = rmn[r];
        v = fminf(v, __shfl_xor(v, 1, 64));
        v = fminf(v, __shfl_xor(v, 2, 64));
        v = fminf(v, __shfl_xor(v, 4, 64));
        v = fminf(v, __shfl_xor(v, 8, 64));
        v = fminf(v, __shfl_xor(v, 16, 64));
        if (l31 == 0) {
            // C/D row map (32x32): row = (reg&3) + 8*(reg>>2) + 4*(lane>>5)
            int row = wave * 32 + (r & 3) + 8 * (r >> 2) + 4 * kh;
            rowplane[row] = v;
        }
    }
}

// ws now holds FINAL per-point mins: plain sum + pose loss in last block.
__global__ __launch_bounds__(256) void reduce_finalize2(
    const float* __restrict__ ws, const float* __restrict__ logits,
    float* __restrict__ out, unsigned int* __restrict__ counter) {
    float s1 = 0.0f, s2 = 0.0f;
    const int tot = NQD1 + NQD2;
    for (int i = blockIdx.x * 256 + threadIdx.x; i < tot;
         i += RED_BLOCKS * 256) {
        float v = ws[i];
        if (i < NQD1) s1 += v; else s2 += v;
    }
#pragma unroll
    for (int off = 32; off > 0; off >>= 1) {
        s1 += __shfl_xor(s1, off, 64);
        s2 += __shfl_xor(s2, off, 64);
    }
    __shared__ float a1[4], a2[4];
    __shared__ int last;
    int w = threadIdx.x >> 6;
    if ((threadIdx.x & 63) == 0) { a1[w] = s1; a2[w] = s2; }
    __syncthreads();
    if (threadIdx.x == 0) {
        atomicAdd(&out[2], a1[0] + a1[1] + a1[2] + a1[3]);
        atomicAdd(&out[3], a2[0] + a2[1] + a2[2] + a2[3]);
        __threadfence();
        unsigned done = atomicAdd(counter, 1u);
        last = (done == RED_BLOCKS - 1) ? 1 : 0;
    }
    __syncthreads();
    if (last && threadIdx.x < 64) {
        const int lane = threadIdx.x;
        float pose_part = 0.0f;
        if (lane < BATCH) {
            const float* L = logits + lane * NHYP;
            float mx = L[0];
#pragma unroll 8
            for (int j = 1; j < NHYP; ++j) mx = fmaxf(mx, L[j]);
            float s = 0.0f;
#pragma unroll 8
            for (int j = 0; j < NHYP; ++j) s += expf(L[j] - mx);
            pose_part = L[0] - (mx + logf(s));  // log_prob[b, 0]
        }
#pragma unroll
        for (int off = 8; off > 0; off >>= 1)
            pose_part += __shfl_xor(pose_part, off, 64);
        if (lane == 0) {
            float sum1 = atomicAdd(&out[2], 0.0f);
            float sum2 = atomicAdd(&out[3], 0.0f);
            float shape_loss = sum1 / (float)NQD1 + sum2 / (float)NQD2;
            float pose_loss = -pose_part / (float)BATCH;
            out[0] = 0.4f * pose_loss + 0.6f * shape_loss;
            out[1] = pose_loss;
            out[2] = shape_loss;
            out[3] = shape_loss;  // sdf_loss
            out[4] = shape_loss;  // caption_loss
        }
    }
}

// ================= fallback (tiny ws) =================

__global__ void init_out(float* out) {
    if (threadIdx.x == 0) { out[2] = 0.0f; out[3] = 0.0f; }
}

__device__ __forceinline__ void scan_refs(const float* __restrict__ r, int cnt,
                                          float px, float py, float pz,
                                          float& minv) {
    for (int m = 0; m < cnt; m += 8) {
#pragma unroll
        for (int u = 0; u < 8; ++u) {
            float mx = r[(m + u) * 3 + 0];
            float my = r[(m + u) * 3 + 1];
            float mz = r[(m + u) * 3 + 2];
            float dx = px - mx, dy = py - my, dz = pz - mz;
            float d = fmaf(dz, dz, fmaf(dy, dy, dx * dx));
            minv = fminf(minv, d);
        }
    }
}

__global__ __launch_bounds__(64) void chamfer_sum(
    const float* __restrict__ qa, int na_, const float* __restrict__ qb, int nb_,
    const float* __restrict__ ra, int ma, const float* __restrict__ rb, int mb,
    float* __restrict__ accum) {
    const int b = blockIdx.y;
    const int n = blockIdx.x * 64 + threadIdx.x;
    float px, py, pz;
    if (n < na_) {
        const float* p = qa + ((size_t)b * na_ + n) * 3;
        px = p[0]; py = p[1]; pz = p[2];
    } else {
        const float* p = qb + ((size_t)b * nb_ + (n - na_)) * 3;
        px = p[0]; py = p[1]; pz = p[2];
    }
    float minv = 3.0e38f;
    scan_refs(ra + (size_t)b * ma * 3, ma, px, py, pz, minv);
    if (mb > 0) scan_refs(rb + (size_t)b * mb * 3, mb, px, py, pz, minv);
    float s = minv;
#pragma unroll
    for (int off = 32; off > 0; off >>= 1) s += __shfl_xor(s, off, 64);
    if (threadIdx.x == 0) atomicAdd(accum, s);
}

__global__ __launch_bounds__(64) void finalize_kernel(
    const float* __restrict__ logits, float* __restrict__ out) {
    const int lane = threadIdx.x;
    float pose_part = 0.0f;
    if (lane < BATCH) {
        const float* L = logits + lane * NHYP;
        float mx = L[0];
#pragma unroll 8
        for (int j = 1; j < NHYP; ++j) mx = fmaxf(mx, L[j]);
        float s = 0.0f;
#pragma unroll 8
        for (int j = 0; j < NHYP; ++j) s += expf(L[j] - mx);
        pose_part = L[0] - (mx + logf(s));
    }
#pragma unroll
    for (int off = 8; off > 0; off >>= 1) pose_part += __shfl_xor(pose_part, off, 64);
    if (lane == 0) {
        float shape_loss = out[2] / (float)NQD1 + out[3] / (float)NQD2;
        float pose_loss = -pose_part / (float)BATCH;
        out[0] = 0.4f * pose_loss + 0.6f * shape_loss;
        out[1] = pose_loss;
        out[2] = shape_loss;
        out[3] = shape_loss;
        out[4] = shape_loss;
    }
}

extern "C" void kernel_launch(void* const* d_in, const int* in_sizes, int n_in,
                              void* d_out, int out_size, void* d_ws, size_t ws_size,
                              hipStream_t stream) {
    const float* shape_query = (const float*)d_in[0];  // (16,4096,3)
    const float* logits      = (const float*)d_in[1];  // (16,64)
    const float* prior       = (const float*)d_in[5];  // (16,1024,3)
    const float* model       = (const float*)d_in[6];  // (16,4096,3)
    float* out = (float*)d_out;

    if (ws_size >= WS_BYTES) {
        float* ws = (float*)d_ws;
        unsigned int* counter = (unsigned int*)ws + (WS_WORDS - 1);
        hipLaunchKernelGGL(chamfer_hp, dim3(GBLOCKS), dim3(256), 0, stream,
                           shape_query, prior, model, ws, out);
        hipLaunchKernelGGL(reduce_finalize2, dim3(RED_BLOCKS), dim3(256), 0,
                           stream, ws, logits, out, counter);
    } else {
        hipLaunchKernelGGL(init_out, dim3(1), dim3(64), 0, stream, out);
        hipLaunchKernelGGL(chamfer_sum,
                           dim3(NREC / 64, BATCH), dim3(64), 0, stream,
                           shape_query, NQ, prior, NPRIOR,
                           model, NMODEL, (const float*)nullptr, 0, out + 2);
        hipLaunchKernelGGL(chamfer_sum,
                           dim3(NMODEL / 64, BATCH), dim3(64), 0, stream,
                           model, NMODEL, (const float*)nullptr, 0,
                           shape_query, NQ, prior, NPRIOR, out + 3);
        hipLaunchKernelGGL(finalize_kernel, dim3(1), dim3(64), 0, stream,
                           logits, out);
    }
}

// Round 14
// 57.808 us; speedup vs baseline: 1.1819x; 1.0440x over previous
//
#include <hip/hip_runtime.h>
#include <math.h>

// Problem constants (fixed by setup_inputs()):
#define BATCH   16
#define NQ      4096      // shape_query pts per batch
#define NPRIOR  1024      // prior pts per batch
#define NREC    5120      // reconstructed = concat(shape_query, prior)
#define NMODEL  4096      // model pts per batch
#define NHYP    64

#define NQD1    (BATCH*NREC)        // 81920 dist1 outputs (rec side)
#define NQD2    (BATCH*NMODEL)      // 65536 dist2 outputs (model side)

// FROZEN validated shape (rounds 8/11/13): 128 rows/block, 4 waves x 32
// rows, 1 A-frag/wave, 2 MFMA + 16 v_min3 per 64-col step. 256-row A
// staging is known-broken (rounds 9/10/12) -- do not revisit.
// Round 14: 2 col-chunks per pass (grid 1152->2304, capacity-bound) and
// register-prefetched B staging (issue-early / write-late, T14 pattern).
#define TILE_COLS 512
#define P1_ROWBLKS (NREC/128)        // 40
#define P2_ROWBLKS (NMODEL/128)      // 32
#define P1_CHUNKS 2
#define P2_CHUNKS 2
#define P1_NTILES (NMODEL/TILE_COLS/P1_CHUNKS)   // 4 tiles / chunk
#define P2_NTILES (NREC/TILE_COLS/P2_CHUNKS)     // 5 tiles / chunk
#define P1_BLOCKS (BATCH*P1_ROWBLKS*P1_CHUNKS)   // 1280
#define P2_BLOCKS (BATCH*P2_ROWBLKS*P2_CHUNKS)   // 1024
#define GBLOCKS   (P1_BLOCKS + P2_BLOCKS)        // 2304

#define WS_WORDS (P1_CHUNKS*NQD1 + P2_CHUNKS*NQD2 + 1)  // 294913 (~1.18 MB)
#define WS_BYTES ((size_t)WS_WORDS*4)
#define RED_BLOCKS 128

typedef _Float16 half8  __attribute__((ext_vector_type(8)));
typedef float    f32x16 __attribute__((ext_vector_type(16)));

// Single-instruction 3-input min (VOP3).
__device__ __forceinline__ float min3f(float a, float b, float c) {
    float d;
    asm("v_min3_f32 %0, %1, %2, %3" : "=v"(d) : "v"(a), "v"(b), "v"(c));
    return d;
}

// Full-precision f16 packing (validated rounds 8/11/13, absmax 0.0):
// d = nq + nr - 2 q.r using all 16 K-slots of the 32x32x16 MFMA.
//   hi-slots: (-2q)_h*r_h (x,y,z), nq_h*1, 1*nr_h, (-2q)_h*r_l (x,y,z)
//   lo-slots: (-2q)_l*r_h (x,y,z), nq_l*1, 1*nr_l, 0,0,0
__device__ __forceinline__ void packQ2(float x, float y, float z,
                                       half8& hi, half8& lo) {
    float n = fmaf(z, z, fmaf(y, y, x * x));
    float mx = -2.0f * x, my = -2.0f * y, mz = -2.0f * z;
    _Float16 xh = (_Float16)mx, yh = (_Float16)my, zh = (_Float16)mz;
    _Float16 nh = (_Float16)n;
    _Float16 xl = (_Float16)(mx - (float)xh);
    _Float16 yl = (_Float16)(my - (float)yh);
    _Float16 zl = (_Float16)(mz - (float)zh);
    _Float16 nl = (_Float16)(n - (float)nh);
    hi[0] = xh; hi[1] = yh; hi[2] = zh; hi[3] = nh;
    hi[4] = (_Float16)1.0f; hi[5] = xh; hi[6] = yh; hi[7] = zh;
    lo[0] = xl; lo[1] = yl; lo[2] = zl; lo[3] = nl;
    lo[4] = (_Float16)1.0f; lo[5] = (_Float16)0.0f;
    lo[6] = (_Float16)0.0f; lo[7] = (_Float16)0.0f;
}
__device__ __forceinline__ void packR2(float x, float y, float z,
                                       half8& hi, half8& lo) {
    float n = fmaf(z, z, fmaf(y, y, x * x));
    _Float16 xh = (_Float16)x, yh = (_Float16)y, zh = (_Float16)z;
    _Float16 nh = (_Float16)n;
    _Float16 xl = (_Float16)(x - (float)xh);
    _Float16 yl = (_Float16)(y - (float)yh);
    _Float16 zl = (_Float16)(z - (float)zh);
    _Float16 nl = (_Float16)(n - (float)nh);
    hi[0] = xh; hi[1] = yh; hi[2] = zh; hi[3] = (_Float16)1.0f;
    hi[4] = nh; hi[5] = xl; hi[6] = yl; hi[7] = zl;
    lo[0] = xh; lo[1] = yh; lo[2] = zh; lo[3] = (_Float16)1.0f;
    lo[4] = nl; lo[5] = (_Float16)0.0f;
    lo[6] = (_Float16)0.0f; lo[7] = (_Float16)0.0f;
}

__device__ __forceinline__ const float* rec_ptr(
    const float* __restrict__ shape_query, const float* __restrict__ prior,
    int b, int g) {
    return (g < NQ) ? shape_query + ((size_t)b * NQ + g) * 3
                    : prior + ((size_t)b * NPRIOR + (g - NQ)) * 3;
}

// ================= main pass kernel =================
// Per block: 128 rows x one col-chunk, tiled at 512 cols. B staging is
// software-pipelined: tile t+1's raw floats are loaded into registers
// BEFORE computing tile t; pack+ds_write happen after the read-barrier.
// HBM latency hides under the current tile's MFMA/min3 work.
__global__ __launch_bounds__(256) void chamfer_hp(
    const float* __restrict__ shape_query,
    const float* __restrict__ prior,
    const float* __restrict__ model,
    float* __restrict__ ws, float* __restrict__ out) {
    __shared__ half8 Alds2[2 * 128];        // [kh][row]   4 KB
    __shared__ half8 Blds2[2 * TILE_COLS];  // [kh][col]  16 KB

    const int blk = blockIdx.x;
    if (blk == 0 && threadIdx.x == 0) {
        out[2] = 0.0f; out[3] = 0.0f;
        ((unsigned*)ws)[WS_WORDS - 1] = 0u;   // reduce completion counter
    }

    const int t    = threadIdx.x;
    const int wave = t >> 6;
    const int lane = t & 63;
    const int l31  = lane & 31;
    const int kh   = lane >> 5;        // which k-half this lane supplies

    int b, rowbase, colbase0, ntiles;
    float* rowplane;
    const bool pass1 = (blk < P1_BLOCKS);
    if (pass1) {
        b = blk / (P1_ROWBLKS * P1_CHUNKS);
        int rem = blk % (P1_ROWBLKS * P1_CHUNKS);
        int rb = rem / P1_CHUNKS, ck = rem % P1_CHUNKS;
        rowbase = rb * 128;
        colbase0 = ck * (P1_NTILES * TILE_COLS);
        ntiles = P1_NTILES;
        rowplane = ws + (size_t)ck * NQD1 + b * NREC + rowbase;
    } else {
        int j = blk - P1_BLOCKS;
        b = j / (P2_ROWBLKS * P2_CHUNKS);
        int rem = j % (P2_ROWBLKS * P2_CHUNKS);
        int rb = rem / P2_CHUNKS, ck = rem % P2_CHUNKS;
        rowbase = rb * 128;
        colbase0 = ck * (P2_NTILES * TILE_COLS);
        ntiles = P2_NTILES;
        rowplane = ws + (size_t)P1_CHUNKS * NQD1 + (size_t)ck * NQD2
                   + b * NMODEL + rowbase;
    }

    // ---- stage A (128 rows, once) ----
    if (t < 128) {
        const float* p = pass1
            ? rec_ptr(shape_query, prior, b, rowbase + t)
            : model + ((size_t)b * NMODEL + rowbase + t) * 3;
        half8 hi, lo;
        packQ2(p[0], p[1], p[2], hi, lo);
        Alds2[t] = hi; Alds2[128 + t] = lo;
    }

    // ---- prologue: load + stage B tile 0 (2 cols/thread) ----
    {
        const float* p0 = pass1
            ? model + ((size_t)b * NMODEL + colbase0 + t) * 3
            : rec_ptr(shape_query, prior, b, colbase0 + t);
        const float* p1 = pass1
            ? model + ((size_t)b * NMODEL + colbase0 + 256 + t) * 3
            : rec_ptr(shape_query, prior, b, colbase0 + 256 + t);
        half8 hi, lo;
        packR2(p0[0], p0[1], p0[2], hi, lo);
        Blds2[t] = hi; Blds2[TILE_COLS + t] = lo;
        packR2(p1[0], p1[1], p1[2], hi, lo);
        Blds2[256 + t] = hi; Blds2[TILE_COLS + 256 + t] = lo;
    }

    float rmn[16];
#pragma unroll
    for (int r = 0; r < 16; ++r) rmn[r] = 3.0e38f;

    f32x16 cz;
#pragma unroll
    for (int i = 0; i < 16; ++i) cz[i] = 0.0f;

    const int boff = kh * TILE_COLS;   // uniform base + divergent index

    __syncthreads();                   // A + B0 visible

    for (int tile = 0; tile < ntiles; ++tile) {
        // ---- issue tile+1's global loads into registers (early) ----
        float nx0, ny0, nz0, nx1, ny1, nz1;
        const bool more = (tile + 1 < ntiles);
        if (more) {
            const int cb = colbase0 + (tile + 1) * TILE_COLS;
            const float* p0 = pass1
                ? model + ((size_t)b * NMODEL + cb + t) * 3
                : rec_ptr(shape_query, prior, b, cb + t);
            const float* p1 = pass1
                ? model + ((size_t)b * NMODEL + cb + 256 + t) * 3
                : rec_ptr(shape_query, prior, b, cb + 256 + t);
            nx0 = p0[0]; ny0 = p0[1]; nz0 = p0[2];
            nx1 = p1[0]; ny1 = p1[1]; nz1 = p1[2];
        }

        // ---- compute current tile: 8 iters of 64 cols ----
        half8 af = Alds2[kh * 128 + wave * 32 + l31];
        half8 bfa = Blds2[boff + l31];
        half8 bfb = Blds2[boff + 32 + l31];
#pragma unroll 2
        for (int it = 0; it < TILE_COLS / 64; ++it) {
            const int nxt = (it == TILE_COLS / 64 - 1) ? 0 : (it + 1) * 64;
            half8 bfa_n = Blds2[boff + nxt + l31];
            half8 bfb_n = Blds2[boff + nxt + 32 + l31];
            f32x16 da = __builtin_amdgcn_mfma_f32_32x32x16_f16(af, bfa, cz, 0, 0, 0);
            f32x16 db = __builtin_amdgcn_mfma_f32_32x32x16_f16(af, bfb, cz, 0, 0, 0);
#pragma unroll
            for (int r = 0; r < 16; ++r) rmn[r] = min3f(rmn[r], da[r], db[r]);
            bfa = bfa_n; bfb = bfb_n;
        }

        __syncthreads();               // all reads of this tile done
        if (more) {
            // ---- pack + write tile+1 (loads have drained under compute) --
            half8 hi, lo;
            packR2(nx0, ny0, nz0, hi, lo);
            Blds2[t] = hi; Blds2[TILE_COLS + t] = lo;
            packR2(nx1, ny1, nz1, hi, lo);
            Blds2[256 + t] = hi; Blds2[TILE_COLS + 256 + t] = lo;
            __syncthreads();           // writes visible
        }
    }

    // ---- epilogue: butterfly min over cols (lane&31), write 32 rows ----
#pragma unroll
    for (int r = 0; r < 16; ++r) {
        float v = rmn[r];
        v = fminf(v, __shfl_xor(v, 1, 64));
        v = fminf(v, __shfl_xor(v, 2, 64));
        v = fminf(v, __shfl_xor(v, 4, 64));
        v = fminf(v, __shfl_xor(v, 8, 64));
        v = fminf(v, __shfl_xor(v, 16, 64));
        if (l31 == 0) {
            // C/D row map (32x32): row = (reg&3) + 8*(reg>>2) + 4*(lane>>5)
            int row = wave * 32 + (r & 3) + 8 * (r >> 2) + 4 * kh;
            rowplane[row] = v;
        }
    }
}

// Min over the 2 partial planes per side, sum; last block computes the
// pose loss and writes all 5 outputs.
__global__ __launch_bounds__(256) void reduce_finalize2(
    const float* __restrict__ ws, const float* __restrict__ logits,
    float* __restrict__ out, unsigned int* __restrict__ counter) {
    const float* p1 = ws;
    const float* p2 = ws + (size_t)P1_CHUNKS * NQD1;
    float s1 = 0.0f, s2 = 0.0f;
    const int tot = NQD1 + NQD2;
    for (int i = blockIdx.x * 256 + threadIdx.x; i < tot;
         i += RED_BLOCKS * 256) {
        if (i < NQD1) {
            s1 += fminf(p1[i], p1[NQD1 + i]);
        } else {
            int j = i - NQD1;
            s2 += fminf(p2[j], p2[NQD2 + j]);
        }
    }
#pragma unroll
    for (int off = 32; off > 0; off >>= 1) {
        s1 += __shfl_xor(s1, off, 64);
        s2 += __shfl_xor(s2, off, 64);
    }
    __shared__ float a1[4], a2[4];
    __shared__ int last;
    int w = threadIdx.x >> 6;
    if ((threadIdx.x & 63) == 0) { a1[w] = s1; a2[w] = s2; }
    __syncthreads();
    if (threadIdx.x == 0) {
        atomicAdd(&out[2], a1[0] + a1[1] + a1[2] + a1[3]);
        atomicAdd(&out[3], a2[0] + a2[1] + a2[2] + a2[3]);
        __threadfence();
        unsigned done = atomicAdd(counter, 1u);
        last = (done == RED_BLOCKS - 1) ? 1 : 0;
    }
    __syncthreads();
    if (last && threadIdx.x < 64) {
        const int lane = threadIdx.x;
        float pose_part = 0.0f;
        if (lane < BATCH) {
            const float* L = logits + lane * NHYP;
            float mx = L[0];
#pragma unroll 8
            for (int j = 1; j < NHYP; ++j) mx = fmaxf(mx, L[j]);
            float s = 0.0f;
#pragma unroll 8
            for (int j = 0; j < NHYP; ++j) s += expf(L[j] - mx);
            pose_part = L[0] - (mx + logf(s));  // log_prob[b, 0]
        }
#pragma unroll
        for (int off = 8; off > 0; off >>= 1)
            pose_part += __shfl_xor(pose_part, off, 64);
        if (lane == 0) {
            float sum1 = atomicAdd(&out[2], 0.0f);
            float sum2 = atomicAdd(&out[3], 0.0f);
            float shape_loss = sum1 / (float)NQD1 + sum2 / (float)NQD2;
            float pose_loss = -pose_part / (float)BATCH;
            out[0] = 0.4f * pose_loss + 0.6f * shape_loss;
            out[1] = pose_loss;
            out[2] = shape_loss;
            out[3] = shape_loss;  // sdf_loss
            out[4] = shape_loss;  // caption_loss
        }
    }
}

// ================= fallback (tiny ws) =================

__global__ void init_out(float* out) {
    if (threadIdx.x == 0) { out[2] = 0.0f; out[3] = 0.0f; }
}

__device__ __forceinline__ void scan_refs(const float* __restrict__ r, int cnt,
                                          float px, float py, float pz,
                                          float& minv) {
    for (int m = 0; m < cnt; m += 8) {
#pragma unroll
        for (int u = 0; u < 8; ++u) {
            float mx = r[(m + u) * 3 + 0];
            float my = r[(m + u) * 3 + 1];
            float mz = r[(m + u) * 3 + 2];
            float dx = px - mx, dy = py - my, dz = pz - mz;
            float d = fmaf(dz, dz, fmaf(dy, dy, dx * dx));
            minv = fminf(minv, d);
        }
    }
}

__global__ __launch_bounds__(64) void chamfer_sum(
    const float* __restrict__ qa, int na_, const float* __restrict__ qb, int nb_,
    const float* __restrict__ ra, int ma, const float* __restrict__ rb, int mb,
    float* __restrict__ accum) {
    const int b = blockIdx.y;
    const int n = blockIdx.x * 64 + threadIdx.x;
    float px, py, pz;
    if (n < na_) {
        const float* p = qa + ((size_t)b * na_ + n) * 3;
        px = p[0]; py = p[1]; pz = p[2];
    } else {
        const float* p = qb + ((size_t)b * nb_ + (n - na_)) * 3;
        px = p[0]; py = p[1]; pz = p[2];
    }
    float minv = 3.0e38f;
    scan_refs(ra + (size_t)b * ma * 3, ma, px, py, pz, minv);
    if (mb > 0) scan_refs(rb + (size_t)b * mb * 3, mb, px, py, pz, minv);
    float s = minv;
#pragma unroll
    for (int off = 32; off > 0; off >>= 1) s += __shfl_xor(s, off, 64);
    if (threadIdx.x == 0) atomicAdd(accum, s);
}

__global__ __launch_bounds__(64) void finalize_kernel(
    const float* __restrict__ logits, float* __restrict__ out) {
    const int lane = threadIdx.x;
    float pose_part = 0.0f;
    if (lane < BATCH) {
        const float* L = logits + lane * NHYP;
        float mx = L[0];
#pragma unroll 8
        for (int j = 1; j < NHYP; ++j) mx = fmaxf(mx, L[j]);
        float s = 0.0f;
#pragma unroll 8
        for (int j = 0; j < NHYP; ++j) s += expf(L[j] - mx);
        pose_part = L[0] - (mx + logf(s));
    }
#pragma unroll
    for (int off = 8; off > 0; off >>= 1) pose_part += __shfl_xor(pose_part, off, 64);
    if (lane == 0) {
        float shape_loss = out[2] / (float)NQD1 + out[3] / (float)NQD2;
        float pose_loss = -pose_part / (float)BATCH;
        out[0] = 0.4f * pose_loss + 0.6f * shape_loss;
        out[1] = pose_loss;
        out[2] = shape_loss;
        out[3] = shape_loss;
        out[4] = shape_loss;
    }
}

extern "C" void kernel_launch(void* const* d_in, const int* in_sizes, int n_in,
                              void* d_out, int out_size, void* d_ws, size_t ws_size,
                              hipStream_t stream) {
    const float* shape_query = (const float*)d_in[0];  // (16,4096,3)
    const float* logits      = (const float*)d_in[1];  // (16,64)
    const float* prior       = (const float*)d_in[5];  // (16,1024,3)
    const float* model       = (const float*)d_in[6];  // (16,4096,3)
    float* out = (float*)d_out;

    if (ws_size >= WS_BYTES) {
        float* ws = (float*)d_ws;
        unsigned int* counter = (unsigned int*)ws + (WS_WORDS - 1);
        hipLaunchKernelGGL(chamfer_hp, dim3(GBLOCKS), dim3(256), 0, stream,
                           shape_query, prior, model, ws, out);
        hipLaunchKernelGGL(reduce_finalize2, dim3(RED_BLOCKS), dim3(256), 0,
                           stream, ws, logits, out, counter);
    } else {
        hipLaunchKernelGGL(init_out, dim3(1), dim3(64), 0, stream, out);
        hipLaunchKernelGGL(chamfer_sum,
                           dim3(NREC / 64, BATCH), dim3(64), 0, stream,
                           shape_query, NQ, prior, NPRIOR,
                           model, NMODEL, (const float*)nullptr, 0, out + 2);
        hipLaunchKernelGGL(chamfer_sum,
                           dim3(NMODEL / 64, BATCH), dim3(64), 0, stream,
                           model, NMODEL, (const float*)nullptr, 0,
                           shape_query, NQ, prior, NPRIOR, out + 3);
        hipLaunchKernelGGL(finalize_kernel, dim3(1), dim3(64), 0, stream,
                           logits, out);
    }
}